// Round 7
// baseline (137.768 us; speedup 1.0000x reference)
//
#include <hip/hip_runtime.h>
#include <hip/hip_fp16.h>

#define NQ   12
#define DIM  4096      // 2^NQ
#define NL   2
#define BATCH 4096

typedef _Float16 half8  __attribute__((ext_vector_type(8)));
typedef float    f32x16 __attribute__((ext_vector_type(16)));
typedef __fp16   hv2    __attribute__((ext_vector_type(2)));

// ---------------------------------------------------------------------------
// Round-7 = Round-6 with the stationary-fragment OFFSET FIX:
// ws arrays live at half-index 0 / 8192 / 16384 = uint4 0 / 1024 / 2048,
// but qc_sim read m1f at wsv[512+..] and m2f at wsv[1024+..] -> GEMM2 used
// garbage gate matrices (absmax 4.2e-3 == p_max, the misplacement signature).
// All layout math re-audited and unchanged.
//
// Round-6 design: MFMA reformulation. v_pk_fma_f16 issues at the f32 rate
// (R0 vs R5 VALUBusy evidence) -> butterfly VALU floor ~25us; matrix cores
// are 16x. Y = B X A^T per sample: X = 64x64 (row=idx bits 11..6, col=5..0),
// A = kron(G6..G11), B = kron(G0..G5), complex 64x64.
//   GEMM1 (X real): T_ext = X * [Ar|Ai]^T  (64x128 = [Tr|Ti])
//   GEMM2: Yr = [Br|-Bi]*Tc, Yi = [Bi|Br]*Tc, Tc = [Tr;Ti] (128x64)
// 24 MFMA 32x32x16_f16 (f32 acc) per wave per sample -> MFMA pipe ~1.3us
// total; kernel becomes HBM-bound (~128MB -> ~20us floor).
// Fragment maps: A row=lane&31, B col=lane&31, k-slot kappa(hi,j)=hi*8+j used
// consistently on BOTH operands (HW k-permutation cancels); C/D col=lane&31,
// row=(reg&3)+8*(reg>>2)+4*(lane>>5) [doc-verified on gfx950].
// LDS: Xh 8KB row-major fp16 + Tc 16KB col-major fp16, granule-XOR swizzled.
// Precision: fp16 operands, f32 accum, 2 rounding layers -> absmax 2-5e-5.
// ---------------------------------------------------------------------------

union U4H8 { uint4 u; half8 h; };

__device__ __forceinline__ unsigned pkrtz(float a, float b) {
    union { hv2 h; unsigned u; } c;
    c.h = __builtin_amdgcn_cvt_pkrtz(a, b);
    return c.u;
}

__global__ void build_gates(const float* __restrict__ th,
                            const float* __restrict__ ph,
                            const float* __restrict__ lm,
                            unsigned short* __restrict__ ws) {
    __shared__ float g[12][8];   // per-qubit fused gate: 00r,00i,01r,01i,10r,...
    int t = threadIdx.x;
    if (t < NQ) {
        int q = t;
        float g00r = 1.f, g00i = 0.f, g01r = 0.f, g01i = 0.f;
        float g10r = 0.f, g10i = 0.f, g11r = 1.f, g11i = 0.f;
        #pragma unroll
        for (int l = 0; l < NL; ++l) {
            float th2 = 0.5f * th[l * NQ + q];
            float p   = ph[l * NQ + q];
            float la  = lm[l * NQ + q];
            float s, c, sl, cl, sp, cp, spl, cpl;
            sincosf(th2, &s, &c);
            sincosf(la, &sl, &cl);
            sincosf(p, &sp, &cp);
            sincosf(p + la, &spl, &cpl);
            float u00r = c,        u00i = 0.f;
            float u01r = -cl * s,  u01i = -sl * s;
            float u10r = cp * s,   u10i = sp * s;
            float u11r = cpl * c,  u11i = spl * c;
            float n00r = u00r*g00r - u00i*g00i + u01r*g10r - u01i*g10i;
            float n00i = u00r*g00i + u00i*g00r + u01r*g10i + u01i*g10r;
            float n01r = u00r*g01r - u00i*g01i + u01r*g11r - u01i*g11i;
            float n01i = u00r*g01i + u00i*g01r + u01r*g11i + u01i*g11r;
            float n10r = u10r*g00r - u10i*g00i + u11r*g10r - u11i*g10i;
            float n10i = u10r*g00i + u10i*g00r + u11r*g10i + u11i*g10r;
            float n11r = u10r*g01r - u10i*g01i + u11r*g11r - u11i*g11i;
            float n11i = u10r*g01i + u10i*g01r + u11r*g11i + u11i*g11r;
            g00r = n00r; g00i = n00i; g01r = n01r; g01i = n01i;
            g10r = n10r; g10i = n10i; g11r = n11r; g11i = n11i;
        }
        g[q][0] = g00r; g[q][1] = g00i; g[q][2] = g01r; g[q][3] = g01i;
        g[q][4] = g10r; g[q][5] = g10i; g[q][6] = g11r; g[q][7] = g11i;
    }
    __syncthreads();

    // Fill 3 fragment-packed arrays (half idx = arr*8192 + frag*512 + lane*8 + j):
    //  arr0 (G1B, GEMM1 B-op): frag = n4*4+ks; nn = n4*32+(lane&31),
    //        k = ks*16+(lane>>5)*8+j; val = nn<64 ? Re A[nn][k] : Im A[nn-64][k]
    //  arr1 (M1, GEMM2 A-op): frag = m*8+ks; r = m*32+(lane&31),
    //        k = ks*16+(lane>>5)*8+j; val = k<64 ? Re B[r][k] : -Im B[r][k-64]
    //  arr2 (M2): val = k<64 ? Im B[r][k] : Re B[r][k-64]
    for (int idx = t; idx < 24576; idx += 256) {
        int arr  = idx >> 13;
        int rem  = idx & 8191;
        int frag = rem >> 9;
        int lane = (rem >> 3) & 63;
        int j    = rem & 7;
        int row, col, base, k, nn = 0;
        if (arr == 0) {
            int n4 = frag >> 2, ks = frag & 3;
            nn  = n4 * 32 + (lane & 31);
            k   = ks * 16 + ((lane >> 5) << 3) + j;   // c'
            row = nn & 63; col = k; base = 6;          // A = kron(G6..G11)
        } else {
            int m = frag >> 3, ks = frag & 7;
            row = m * 32 + (lane & 31);                // r
            k   = ks * 16 + ((lane >> 5) << 3) + j;
            col = k & 63; base = 0;                    // B = kron(G0..G5)
        }
        float re = 1.f, im = 0.f;
        #pragma unroll
        for (int qq = 0; qq < 6; ++qq) {
            const float* G = g[base + qq];
            int rb = (row >> (5 - qq)) & 1;
            int cb = (col >> (5 - qq)) & 1;
            float fr = G[rb * 4 + cb * 2], fi = G[rb * 4 + cb * 2 + 1];
            float nre = re * fr - im * fi;
            float nim = re * fi + im * fr;
            re = nre; im = nim;
        }
        float val;
        if (arr == 0)      val = (nn < 64) ? re : im;
        else if (arr == 1) val = (k < 64) ? re : -im;
        else               val = (k < 64) ? im :  re;
        union { __fp16 h; unsigned short s; } cv;
        cv.h = (__fp16)val;
        ws[idx] = cv.s;
    }
}

__global__ __launch_bounds__(256, 2)
void qc_sim(const float* __restrict__ in,
            const unsigned short* __restrict__ gw,
            float* __restrict__ out) {
    __shared__ unsigned Xh32[2048];   // 8 KB: X fp16, row-major, granule-swz
    __shared__ unsigned Tc32[4096];   // 16 KB: Tc fp16, col-major, granule-swz
    __shared__ float red[4];

    const int t = threadIdx.x, lane = t & 63, w = t >> 6, b = blockIdx.x;
    const int m1 = w & 1, ng = (w >> 1) * 2;   // GEMM1: m-tile, n-tiles ng,ng+1
    const int m2 = w & 1, n2 = w >> 1;         // GEMM2: (m,n) quarter of Y

    // ---- stationary fragment loads (arr bases: uint4 0 / 1024 / 2048) ----
    const uint4* __restrict__ wsv = reinterpret_cast<const uint4*>(gw);
    uint4 g1b[2][4], m1f[8], m2f[8];
    #pragma unroll
    for (int n = 0; n < 2; ++n)
        #pragma unroll
        for (int ks = 0; ks < 4; ++ks)
            g1b[n][ks] = wsv[((ng + n) * 4 + ks) * 64 + lane];
    #pragma unroll
    for (int ks = 0; ks < 8; ++ks) m1f[ks] = wsv[1024 + (m2 * 8 + ks) * 64 + lane];
    #pragma unroll
    for (int ks = 0; ks < 8; ++ks) m2f[ks] = wsv[2048 + (m2 * 8 + ks) * 64 + lane];

    // ---- load input sample (coalesced float4) ----
    const float4* __restrict__ x4 =
        reinterpret_cast<const float4*>(in + (size_t)b * DIM);
    float4 lX[4];
    #pragma unroll
    for (int j = 0; j < 4; ++j) lX[j] = x4[j * 256 + t];

    // ---- sumsq (f32, exact) ----
    float ss = 0.f;
    #pragma unroll
    for (int j = 0; j < 4; ++j)
        ss += lX[j].x*lX[j].x + lX[j].y*lX[j].y + lX[j].z*lX[j].z + lX[j].w*lX[j].w;
    #pragma unroll
    for (int off = 32; off > 0; off >>= 1) ss += __shfl_down(ss, off, 64);
    if (lane == 0) red[w] = ss;

    // ---- stage X -> LDS fp16, swizzled: word = r*32+((cg^(r&7))<<2)+(c&7)/2
    #pragma unroll
    for (int j = 0; j < 4; ++j) {
        int fi = (j * 256 + t) * 4, r = fi >> 6, c = fi & 63;
        int a32 = r * 32 + ((((c >> 3) ^ (r & 7)) << 2)) + ((c & 7) >> 1);
        Xh32[a32]     = pkrtz(lX[j].x, lX[j].y);
        Xh32[a32 + 1] = pkrtz(lX[j].z, lX[j].w);
    }
    __syncthreads();
    const float inv = 1.0f / (red[0] + red[1] + red[2] + red[3]);

    // ---- GEMM1: T_ext = X * [Ar|Ai]^T  (this wave: m1, n-tiles ng,ng+1) ----
    f32x16 acc0 = {0,0,0,0,0,0,0,0,0,0,0,0,0,0,0,0};
    f32x16 acc1 = {0,0,0,0,0,0,0,0,0,0,0,0,0,0,0,0};
    const int rowX = m1 * 32 + (lane & 31);
    #pragma unroll
    for (int ks = 0; ks < 4; ++ks) {
        int kb  = ks * 16 + ((lane >> 5) << 3);
        int a32 = rowX * 32 + ((((kb >> 3) ^ (rowX & 7)) << 2));
        U4H8 xf; xf.u = *reinterpret_cast<const uint4*>(&Xh32[a32]);
        U4H8 b0; b0.u = g1b[0][ks];
        U4H8 b1; b1.u = g1b[1][ks];
        acc0 = __builtin_amdgcn_mfma_f32_32x32x16_f16(xf.h, b0.h, acc0, 0, 0, 0);
        acc1 = __builtin_amdgcn_mfma_f32_32x32x16_f16(xf.h, b1.h, acc1, 0, 0, 0);
    }

    // ---- write Tc = [Tr;Ti] (128x64, col-major, swizzled) ----
    #pragma unroll
    for (int tile = 0; tile < 2; ++tile) {
        int nt = ng + tile;
        const f32x16& acc = tile ? acc1 : acc0;
        int kofs = m1 * 32 + 64 * (nt >> 1) + ((lane >> 5) << 2);
        int cc   = (nt & 1) * 32 + (lane & 31);
        #pragma unroll
        for (int p = 0; p < 4; ++p) {
            int k0  = kofs + p * 8;
            int a32 = cc * 64 + (((k0 >> 3) ^ (cc & 15)) << 2) + ((k0 & 7) >> 1);
            Tc32[a32]     = pkrtz(acc[4 * p],     acc[4 * p + 1]);
            Tc32[a32 + 1] = pkrtz(acc[4 * p + 2], acc[4 * p + 3]);
        }
    }
    __syncthreads();

    // ---- GEMM2: Yr = M1*Tc, Yi = M2*Tc (this wave: quarter (m2,n2)) ----
    f32x16 accR = {0,0,0,0,0,0,0,0,0,0,0,0,0,0,0,0};
    f32x16 accI = {0,0,0,0,0,0,0,0,0,0,0,0,0,0,0,0};
    const int cT = n2 * 32 + (lane & 31);
    #pragma unroll
    for (int ks = 0; ks < 8; ++ks) {
        int kb  = ks * 16 + ((lane >> 5) << 3);
        int a32 = cT * 64 + (((kb >> 3) ^ (cT & 15)) << 2);
        U4H8 tf; tf.u = *reinterpret_cast<const uint4*>(&Tc32[a32]);
        U4H8 a1; a1.u = m1f[ks];
        U4H8 a2; a2.u = m2f[ks];
        accR = __builtin_amdgcn_mfma_f32_32x32x16_f16(a1.h, tf.h, accR, 0, 0, 0);
        accI = __builtin_amdgcn_mfma_f32_32x32x16_f16(a2.h, tf.h, accI, 0, 0, 0);
    }

    // ---- epilogue: prob = (Yr^2+Yi^2)*inv; C/D row=(r&3)+8*(r>>2)+4*(l>>5)
    float* __restrict__ o = out + (size_t)b * DIM
        + (size_t)((m2 * 32 + ((lane >> 5) << 2)) * 64 + n2 * 32 + (lane & 31));
    #pragma unroll
    for (int r = 0; r < 16; ++r) {
        int off = ((r & 3) + 8 * (r >> 2)) * 64;
        o[off] = (accR[r] * accR[r] + accI[r] * accI[r]) * inv;
    }
}

extern "C" void kernel_launch(void* const* d_in, const int* in_sizes, int n_in,
                              void* d_out, int out_size, void* d_ws, size_t ws_size,
                              hipStream_t stream) {
    (void)in_sizes; (void)n_in; (void)out_size; (void)ws_size;
    const float* inputs = (const float*)d_in[0];
    const float* thetas = (const float*)d_in[1];
    const float* phis   = (const float*)d_in[2];
    const float* lams   = (const float*)d_in[3];
    unsigned short* gates = (unsigned short*)d_ws;   // 48 KB fragment-packed
    float* out = (float*)d_out;

    hipLaunchKernelGGL(build_gates, dim3(1), dim3(256), 0, stream,
                       thetas, phis, lams, gates);
    hipLaunchKernelGGL(qc_sim, dim3(BATCH), dim3(256), 0, stream,
                       inputs, gates, out);
}

// Round 8
// 123.508 us; speedup vs baseline: 1.1155x; 1.1155x over previous
//
#include <hip/hip_runtime.h>
#include <hip/hip_fp16.h>

#define NQ   12
#define DIM  4096      // 2^NQ
#define NL   2
#define BATCH 4096
#define SPB  8         // samples per qc_sim block (grid 512 = 2 blocks/CU exact)

typedef _Float16 half8  __attribute__((ext_vector_type(8)));
typedef float    f32x16 __attribute__((ext_vector_type(16)));
typedef __fp16   hv2    __attribute__((ext_vector_type(2)));

// ---------------------------------------------------------------------------
// Round-8: keep round-7's VERIFIED per-sample MFMA math (absmax 3.05e-5)
// byte-identical; fix the two structural costs found in the R7 accounting
// (build_gates + qc_sim ~= 54us):
//  * build_gates was ONE block doing 24576 kron elements serially (96/thread,
//    1 wave/SIMD, dependent complex chains) -> now 96 blocks, 1 elem/thread.
//  * qc_sim reloaded all 48KB of stationary gate fragments per block
//    (~400MB of L2 traffic across 4096 blocks + serial load ramp each block)
//    -> 8 samples per block (grid 512 = exactly 2 resident blocks/CU),
//    fragments loaded ONCE, per-sample loop reuses Xh/Tc LDS.
// Barrier safety (2 per sample, unchanged count): Xh writes for s+1 occur
// after barrier2(s), which waves reach only after GEMM1(s) Xh-reads; Tc
// writes for s+1 occur after barrier1(s+1), after all GEMM2(s) Tc-reads;
// red is read (inv) between barrier1 and GEMM1, i.e. before barrier2, so
// red writes for s+1 (after barrier2(s)) are safe. Next-sample input
// prefetch is issued during the stage phase to hide HBM latency.
//
// Design (R6/R7): Y = B X A^T per sample; X = 64x64 (row=idx bits 11..6,
// col=5..0), A = kron(G6..G11), B = kron(G0..G5).
//   GEMM1 (X real): T_ext = X * [Ar|Ai]^T  (64x128 = [Tr|Ti])
//   GEMM2: Yr = [Br|-Bi]*Tc, Yi = [Bi|Br]*Tc, Tc = [Tr;Ti] (128x64)
// Fragment maps (HW-verified via R7 pass): A row=lane&31, B col=lane&31,
// k-slot kappa(hi,j)=hi*8+j consistent on both operands; C/D col=lane&31,
// row=(reg&3)+8*(reg>>2)+4*(lane>>5).
// LDS: Xh 8KB + Tc 16KB, granule-XOR swizzled. fp16 operands, f32 accum.
// ---------------------------------------------------------------------------

union U4H8 { uint4 u; half8 h; };

__device__ __forceinline__ unsigned pkrtz(float a, float b) {
    union { hv2 h; unsigned u; } c;
    c.h = __builtin_amdgcn_cvt_pkrtz(a, b);
    return c.u;
}

__global__ void build_gates(const float* __restrict__ th,
                            const float* __restrict__ ph,
                            const float* __restrict__ lm,
                            unsigned short* __restrict__ ws) {
    __shared__ float g[12][8];   // per-qubit fused gate: 00r,00i,01r,01i,10r,...
    int t = threadIdx.x;
    if (t < NQ) {
        int q = t;
        float g00r = 1.f, g00i = 0.f, g01r = 0.f, g01i = 0.f;
        float g10r = 0.f, g10i = 0.f, g11r = 1.f, g11i = 0.f;
        #pragma unroll
        for (int l = 0; l < NL; ++l) {
            float th2 = 0.5f * th[l * NQ + q];
            float p   = ph[l * NQ + q];
            float la  = lm[l * NQ + q];
            float s, c, sl, cl, sp, cp, spl, cpl;
            sincosf(th2, &s, &c);
            sincosf(la, &sl, &cl);
            sincosf(p, &sp, &cp);
            sincosf(p + la, &spl, &cpl);
            float u00r = c,        u00i = 0.f;
            float u01r = -cl * s,  u01i = -sl * s;
            float u10r = cp * s,   u10i = sp * s;
            float u11r = cpl * c,  u11i = spl * c;
            float n00r = u00r*g00r - u00i*g00i + u01r*g10r - u01i*g10i;
            float n00i = u00r*g00i + u00i*g00r + u01r*g10i + u01i*g10r;
            float n01r = u00r*g01r - u00i*g01i + u01r*g11r - u01i*g11i;
            float n01i = u00r*g01i + u00i*g01r + u01r*g11i + u01i*g11r;
            float n10r = u10r*g00r - u10i*g00i + u11r*g10r - u11i*g10i;
            float n10i = u10r*g00i + u10i*g00r + u11r*g10i + u11i*g10r;
            float n11r = u10r*g01r - u10i*g01i + u11r*g11r - u11i*g11i;
            float n11i = u10r*g01i + u10i*g01r + u11r*g11i + u11i*g11r;
            g00r = n00r; g00i = n00i; g01r = n01r; g01i = n01i;
            g10r = n10r; g10i = n10i; g11r = n11r; g11i = n11i;
        }
        g[q][0] = g00r; g[q][1] = g00i; g[q][2] = g01r; g[q][3] = g01i;
        g[q][4] = g10r; g[q][5] = g10i; g[q][6] = g11r; g[q][7] = g11i;
    }
    __syncthreads();

    // One element per thread (96 blocks x 256 threads = 24576):
    //  half idx = arr*8192 + frag*512 + lane*8 + j
    //  arr0 (G1B, GEMM1 B-op): frag = n4*4+ks; nn = n4*32+(lane&31),
    //        k = ks*16+(lane>>5)*8+j; val = nn<64 ? Re A[nn][k] : Im A[nn-64][k]
    //  arr1 (M1, GEMM2 A-op): frag = m*8+ks; r = m*32+(lane&31),
    //        k = ks*16+(lane>>5)*8+j; val = k<64 ? Re B[r][k] : -Im B[r][k-64]
    //  arr2 (M2): val = k<64 ? Im B[r][k] : Re B[r][k-64]
    {
        int idx  = blockIdx.x * 256 + t;
        int arr  = idx >> 13;
        int rem  = idx & 8191;
        int frag = rem >> 9;
        int lane = (rem >> 3) & 63;
        int j    = rem & 7;
        int row, col, base, k, nn = 0;
        if (arr == 0) {
            int n4 = frag >> 2, ks = frag & 3;
            nn  = n4 * 32 + (lane & 31);
            k   = ks * 16 + ((lane >> 5) << 3) + j;   // c'
            row = nn & 63; col = k; base = 6;          // A = kron(G6..G11)
        } else {
            int m = frag >> 3, ks = frag & 7;
            row = m * 32 + (lane & 31);                // r
            k   = ks * 16 + ((lane >> 5) << 3) + j;
            col = k & 63; base = 0;                    // B = kron(G0..G5)
        }
        float re = 1.f, im = 0.f;
        #pragma unroll
        for (int qq = 0; qq < 6; ++qq) {
            const float* G = g[base + qq];
            int rb = (row >> (5 - qq)) & 1;
            int cb = (col >> (5 - qq)) & 1;
            float fr = G[rb * 4 + cb * 2], fi = G[rb * 4 + cb * 2 + 1];
            float nre = re * fr - im * fi;
            float nim = re * fi + im * fr;
            re = nre; im = nim;
        }
        float val;
        if (arr == 0)      val = (nn < 64) ? re : im;
        else if (arr == 1) val = (k < 64) ? re : -im;
        else               val = (k < 64) ? im :  re;
        union { __fp16 h; unsigned short s; } cv;
        cv.h = (__fp16)val;
        ws[idx] = cv.s;
    }
}

__global__ __launch_bounds__(256, 2)
void qc_sim(const float* __restrict__ in,
            const unsigned short* __restrict__ gw,
            float* __restrict__ out) {
    __shared__ unsigned Xh32[2048];   // 8 KB: X fp16, row-major, granule-swz
    __shared__ unsigned Tc32[4096];   // 16 KB: Tc fp16, col-major, granule-swz
    __shared__ float red[4];

    const int t = threadIdx.x, lane = t & 63, w = t >> 6, b = blockIdx.x;
    const int m1 = w & 1, ng = (w >> 1) * 2;   // GEMM1: m-tile, n-tiles ng,ng+1
    const int m2 = w & 1, n2 = w >> 1;         // GEMM2: (m,n) quarter of Y

    // ---- stationary fragment loads, ONCE per block (uint4 0/1024/2048) ----
    const uint4* __restrict__ wsv = reinterpret_cast<const uint4*>(gw);
    uint4 g1b[2][4], m1f[8], m2f[8];
    #pragma unroll
    for (int n = 0; n < 2; ++n)
        #pragma unroll
        for (int ks = 0; ks < 4; ++ks)
            g1b[n][ks] = wsv[((ng + n) * 4 + ks) * 64 + lane];
    #pragma unroll
    for (int ks = 0; ks < 8; ++ks) m1f[ks] = wsv[1024 + (m2 * 8 + ks) * 64 + lane];
    #pragma unroll
    for (int ks = 0; ks < 8; ++ks) m2f[ks] = wsv[2048 + (m2 * 8 + ks) * 64 + lane];

    const float* __restrict__ base_in  = in  + (size_t)b * SPB * DIM;
    float*       __restrict__ base_out = out + (size_t)b * SPB * DIM;

    // ---- load first sample (coalesced float4) ----
    float4 cur[4], nxt[4];
    {
        const float4* __restrict__ x4 = reinterpret_cast<const float4*>(base_in);
        #pragma unroll
        for (int j = 0; j < 4; ++j) cur[j] = x4[j * 256 + t];
    }

    for (int s = 0; s < SPB; ++s) {
        // ---- sumsq (f32, exact) ----
        float ss = 0.f;
        #pragma unroll
        for (int j = 0; j < 4; ++j)
            ss += cur[j].x*cur[j].x + cur[j].y*cur[j].y
                + cur[j].z*cur[j].z + cur[j].w*cur[j].w;
        #pragma unroll
        for (int off = 32; off > 0; off >>= 1) ss += __shfl_down(ss, off, 64);
        if (lane == 0) red[w] = ss;

        // ---- stage X -> LDS fp16 (swizzled), then prefetch next sample ----
        #pragma unroll
        for (int j = 0; j < 4; ++j) {
            int fi = (j * 256 + t) * 4, r = fi >> 6, c = fi & 63;
            int a32 = r * 32 + ((((c >> 3) ^ (r & 7)) << 2)) + ((c & 7) >> 1);
            Xh32[a32]     = pkrtz(cur[j].x, cur[j].y);
            Xh32[a32 + 1] = pkrtz(cur[j].z, cur[j].w);
        }
        if (s + 1 < SPB) {
            const float4* __restrict__ xn =
                reinterpret_cast<const float4*>(base_in + (size_t)(s + 1) * DIM);
            #pragma unroll
            for (int j = 0; j < 4; ++j) nxt[j] = xn[j * 256 + t];
        }
        __syncthreads();   // barrier1: X + red visible
        const float inv = 1.0f / (red[0] + red[1] + red[2] + red[3]);

        // ---- GEMM1: T_ext = X * [Ar|Ai]^T (wave: m1, n-tiles ng,ng+1) ----
        f32x16 acc0 = {0,0,0,0,0,0,0,0,0,0,0,0,0,0,0,0};
        f32x16 acc1 = {0,0,0,0,0,0,0,0,0,0,0,0,0,0,0,0};
        const int rowX = m1 * 32 + (lane & 31);
        #pragma unroll
        for (int ks = 0; ks < 4; ++ks) {
            int kb  = ks * 16 + ((lane >> 5) << 3);
            int a32 = rowX * 32 + ((((kb >> 3) ^ (rowX & 7)) << 2));
            U4H8 xf; xf.u = *reinterpret_cast<const uint4*>(&Xh32[a32]);
            U4H8 b0; b0.u = g1b[0][ks];
            U4H8 b1; b1.u = g1b[1][ks];
            acc0 = __builtin_amdgcn_mfma_f32_32x32x16_f16(xf.h, b0.h, acc0, 0, 0, 0);
            acc1 = __builtin_amdgcn_mfma_f32_32x32x16_f16(xf.h, b1.h, acc1, 0, 0, 0);
        }

        // ---- write Tc = [Tr;Ti] (128x64, col-major, swizzled) ----
        #pragma unroll
        for (int tile = 0; tile < 2; ++tile) {
            int nt = ng + tile;
            const f32x16& acc = tile ? acc1 : acc0;
            int kofs = m1 * 32 + 64 * (nt >> 1) + ((lane >> 5) << 2);
            int cc   = (nt & 1) * 32 + (lane & 31);
            #pragma unroll
            for (int p = 0; p < 4; ++p) {
                int k0  = kofs + p * 8;
                int a32 = cc * 64 + (((k0 >> 3) ^ (cc & 15)) << 2) + ((k0 & 7) >> 1);
                Tc32[a32]     = pkrtz(acc[4 * p],     acc[4 * p + 1]);
                Tc32[a32 + 1] = pkrtz(acc[4 * p + 2], acc[4 * p + 3]);
            }
        }
        __syncthreads();   // barrier2: Tc visible

        // ---- GEMM2: Yr = M1*Tc, Yi = M2*Tc (wave: quarter (m2,n2)) ----
        f32x16 accR = {0,0,0,0,0,0,0,0,0,0,0,0,0,0,0,0};
        f32x16 accI = {0,0,0,0,0,0,0,0,0,0,0,0,0,0,0,0};
        const int cT = n2 * 32 + (lane & 31);
        #pragma unroll
        for (int ks = 0; ks < 8; ++ks) {
            int kb  = ks * 16 + ((lane >> 5) << 3);
            int a32 = cT * 64 + (((kb >> 3) ^ (cT & 15)) << 2);
            U4H8 tf; tf.u = *reinterpret_cast<const uint4*>(&Tc32[a32]);
            U4H8 a1; a1.u = m1f[ks];
            U4H8 a2; a2.u = m2f[ks];
            accR = __builtin_amdgcn_mfma_f32_32x32x16_f16(a1.h, tf.h, accR, 0, 0, 0);
            accI = __builtin_amdgcn_mfma_f32_32x32x16_f16(a2.h, tf.h, accI, 0, 0, 0);
        }

        // ---- epilogue: prob = (Yr^2+Yi^2)*inv; C/D row=(r&3)+8*(r>>2)+4*hi
        float* __restrict__ o = base_out + (size_t)s * DIM
            + (size_t)((m2 * 32 + ((lane >> 5) << 2)) * 64 + n2 * 32 + (lane & 31));
        #pragma unroll
        for (int r = 0; r < 16; ++r) {
            int off = ((r & 3) + 8 * (r >> 2)) * 64;
            o[off] = (accR[r] * accR[r] + accI[r] * accI[r]) * inv;
        }

        // ---- rotate prefetched sample into place ----
        if (s + 1 < SPB) {
            #pragma unroll
            for (int j = 0; j < 4; ++j) cur[j] = nxt[j];
        }
    }
}

extern "C" void kernel_launch(void* const* d_in, const int* in_sizes, int n_in,
                              void* d_out, int out_size, void* d_ws, size_t ws_size,
                              hipStream_t stream) {
    (void)in_sizes; (void)n_in; (void)out_size; (void)ws_size;
    const float* inputs = (const float*)d_in[0];
    const float* thetas = (const float*)d_in[1];
    const float* phis   = (const float*)d_in[2];
    const float* lams   = (const float*)d_in[3];
    unsigned short* gates = (unsigned short*)d_ws;   // 48 KB fragment-packed
    float* out = (float*)d_out;

    hipLaunchKernelGGL(build_gates, dim3(96), dim3(256), 0, stream,
                       thetas, phis, lams, gates);
    hipLaunchKernelGGL(qc_sim, dim3(BATCH / SPB), dim3(256), 0, stream,
                       inputs, gates, out);
}